// Round 10
// baseline (239.630 us; speedup 1.0000x reference)
//
#include <hip/hip_runtime.h>

using f32x4  = __attribute__((ext_vector_type(4))) float;
using bf16x4 = __attribute__((ext_vector_type(4))) __bf16;
using bf16x8 = __attribute__((ext_vector_type(8))) __bf16;
using s16x4  = __attribute__((ext_vector_type(4))) short;

__device__ inline void gload16(const void* g, void* l) {
  __builtin_amdgcn_global_load_lds((const __attribute__((address_space(1))) void*)g,
                                   (__attribute__((address_space(3))) void*)l, 16, 0, 0);
}

__device__ inline f32x4 mfma16x16x16bf(bf16x4 a, bf16x4 b, f32x4 c) {
#if __has_builtin(__builtin_amdgcn_mfma_f32_16x16x16_bf16)
  return __builtin_amdgcn_mfma_f32_16x16x16_bf16(a, b, c, 0, 0, 0);
#else
  return __builtin_amdgcn_mfma_f32_16x16x16bf16_1k(__builtin_bit_cast(s16x4, a),
                                                   __builtin_bit_cast(s16x4, b), c, 0, 0, 0);
#endif
}

// ---------------- prep: pack x->bf16, transpose W_attn & W_proj (one launch) ----------------
__global__ __launch_bounds__(256) void prep_kernel(const float* __restrict__ x,
                                                   const float* __restrict__ Wa,
                                                   const float* __restrict__ Wp,
                                                   __bf16* __restrict__ x_bf,
                                                   __bf16* __restrict__ Wa_t,
                                                   __bf16* __restrict__ Wp_t) {
  const int b = blockIdx.x, tid = threadIdx.x;
  if (b < 4096) {  // pack x: 1M f32x4 quads
    int i = b * 256 + tid;
    f32x4 v = ((const f32x4*)x)[i];
    bf16x4 o;
    o[0] = (__bf16)v[0]; o[1] = (__bf16)v[1]; o[2] = (__bf16)v[2]; o[3] = (__bf16)v[3];
    ((bf16x4*)x_bf)[i] = o;
    return;
  }
  __shared__ float tile[32][33];
  const int tx = tid & 31, ty = tid >> 5;
  const float* in; __bf16* out; int R, C, c0, r0;
  if (b < 4096 + 3072) {  // Wa^T: [1024][3072] -> [3072][1024]
    int bx = b - 4096; in = Wa; out = Wa_t; R = 1024; C = 3072;
    c0 = (bx % 96) * 32; r0 = (bx / 96) * 32;
  } else {                // Wp^T
    int bx = b - 7168; in = Wp; out = Wp_t; R = 1024; C = 1024;
    c0 = (bx & 31) * 32; r0 = (bx >> 5) * 32;
  }
  #pragma unroll
  for (int i = 0; i < 32; i += 8)
    tile[ty + i][tx] = in[(size_t)(r0 + ty + i) * C + c0 + tx];
  __syncthreads();
  #pragma unroll
  for (int i = 0; i < 32; i += 8)
    out[(size_t)(c0 + ty + i) * R + r0 + tx] = (__bf16)tile[tx][ty + i];
}

// ---------------- bf16 MFMA GEMM (m97-style): C = A * Bt^T, XCD-swizzled grid ----------------
template <typename OUT>
__global__ __launch_bounds__(256) void gemm_bt_kernel(const __bf16* __restrict__ A,
                                                      const __bf16* __restrict__ Bt,
                                                      OUT* __restrict__ C,
                                                      int M, int N, int K) {
  const int nwg = gridDim.x, flat = blockIdx.x;
  const int cpx = nwg >> 3;
  const int wg = (flat & 7) * cpx + (flat >> 3);
  const int nbn = N >> 7;
  const int bn = (wg % nbn) * 128, bm = (wg / nbn) * 128;

  const int tid = threadIdx.x;
  const int lane = tid & 63, wid = tid >> 6;
  const int wm = (wid >> 1) * 64, wn = (wid & 1) * 64;
  const int l15 = lane & 15, lhi = lane >> 4;
  __shared__ __align__(16) __bf16 As[2][4096];  // [128][32]
  __shared__ __align__(16) __bf16 Bs[2][4096];
  f32x4 acc[4][4] = {};

  const int rrow = wid * 16 + (lane >> 2);
  const int schunk = lane & 3;

  #define G_STAGE(k0_, b_)                                                              \
    {                                                                                   \
      _Pragma("unroll")                                                                 \
      for (int i_ = 0; i_ < 2; ++i_) {                                                  \
        int row_ = i_ * 64 + rrow;                                                      \
        int lch_ = schunk ^ (row_ & 3);                                                 \
        gload16(A + (size_t)(bm + row_) * K + (k0_) + lch_ * 8,                         \
                (char*)&As[b_][0] + i_ * 4096 + wid * 1024);                            \
        gload16(Bt + (size_t)(bn + row_) * K + (k0_) + lch_ * 8,                        \
                (char*)&Bs[b_][0] + i_ * 4096 + wid * 1024);                            \
      }                                                                                 \
    }

  G_STAGE(0, 0);
  __syncthreads();
  const int nk = K >> 5;
  for (int t = 0; t < nk; ++t) {
    const int cur = t & 1;
    if (t + 1 < nk) G_STAGE((t + 1) * 32, cur ^ 1);
    bf16x8 af[4], bfr[4];
    #pragma unroll
    for (int i = 0; i < 4; ++i) {
      int row = wm + i * 16 + l15;
      af[i] = *(const bf16x8*)&As[cur][row * 32 + ((lhi ^ (row & 3)) * 8)];
    }
    #pragma unroll
    for (int j = 0; j < 4; ++j) {
      int row = wn + j * 16 + l15;
      bfr[j] = *(const bf16x8*)&Bs[cur][row * 32 + ((lhi ^ (row & 3)) * 8)];
    }
    #pragma unroll
    for (int i = 0; i < 4; ++i)
      #pragma unroll
      for (int j = 0; j < 4; ++j)
        acc[i][j] = __builtin_amdgcn_mfma_f32_16x16x32_bf16(af[i], bfr[j], acc[i][j], 0, 0, 0);
    __syncthreads();
  }
  #pragma unroll
  for (int i = 0; i < 4; ++i)
    #pragma unroll
    for (int j = 0; j < 4; ++j)
      #pragma unroll
      for (int r = 0; r < 4; ++r)
        C[(size_t)(bm + wm + i * 16 + lhi * 4 + r) * N + (bn + wn + j * 16 + l15)] =
            (OUT)acc[i][j][r];
  #undef G_STAGE
}

// ---------------- postproc: RoPE+pack q; K,V^T -> swizzled 64x64 tiles ----------------
__global__ __launch_bounds__(256) void postproc_kernel(const __bf16* __restrict__ qkv,
                                                       const float* __restrict__ fc,
                                                       const float* __restrict__ fs,
                                                       __bf16* __restrict__ qb,
                                                       __bf16* __restrict__ kst,
                                                       __bf16* __restrict__ vst) {
  const int ktile = blockIdx.x, h = blockIdx.y;
  const int tid = threadIdx.x;
  const int row = tid >> 2, seg = tid & 3;
  const int t = ktile * 64 + row;
  __shared__ __bf16 vt[64][72];

  float cs[8], sn[8];
  #pragma unroll
  for (int p = 0; p < 8; ++p) {
    cs[p] = fc[t * 32 + seg * 8 + p];
    sn[p] = fs[t * 32 + seg * 8 + p];
  }
  const float QS = 0.125f * 1.4426950408889634f;  // 1/sqrt(64) * log2(e)

  {
    const __bf16* src = qkv + (size_t)t * 3072 + h * 64 + seg * 16;
    bf16x8 a = *(const bf16x8*)src, b = *(const bf16x8*)(src + 8);
    float v[16];
    #pragma unroll
    for (int i = 0; i < 8; ++i) { v[i] = (float)a[i]; v[8 + i] = (float)b[i]; }
    __bf16 ob[16];
    #pragma unroll
    for (int p = 0; p < 8; ++p) {
      ob[2 * p]     = (__bf16)((v[2 * p] * cs[p] - v[2 * p + 1] * sn[p]) * QS);
      ob[2 * p + 1] = (__bf16)((v[2 * p] * sn[p] + v[2 * p + 1] * cs[p]) * QS);
    }
    __bf16* dst = qb + (size_t)t * 1024 + h * 64 + seg * 16;
    *(bf16x8*)dst = *(bf16x8*)ob;
    *(bf16x8*)(dst + 8) = *(bf16x8*)(ob + 8);
  }
  {
    const __bf16* src = qkv + (size_t)t * 3072 + 1024 + h * 64 + seg * 16;
    bf16x8 a = *(const bf16x8*)src, b = *(const bf16x8*)(src + 8);
    float v[16];
    #pragma unroll
    for (int i = 0; i < 8; ++i) { v[i] = (float)a[i]; v[8 + i] = (float)b[i]; }
    __bf16 ob[16];
    #pragma unroll
    for (int p = 0; p < 8; ++p) {
      ob[2 * p]     = (__bf16)(v[2 * p] * cs[p] - v[2 * p + 1] * sn[p]);
      ob[2 * p + 1] = (__bf16)(v[2 * p] * sn[p] + v[2 * p + 1] * cs[p]);
    }
    __bf16* kdst = kst + ((size_t)(h * 64 + ktile)) * 4096 + row * 64;
    const int r7 = row & 7;
    *(bf16x8*)(kdst + ((seg * 2) ^ r7) * 8)     = *(bf16x8*)ob;
    *(bf16x8*)(kdst + ((seg * 2 + 1) ^ r7) * 8) = *(bf16x8*)(ob + 8);
  }
  {
    const __bf16* src = qkv + (size_t)t * 3072 + 2048 + h * 64 + seg * 16;
    *(bf16x8*)&vt[row][seg * 16]     = *(const bf16x8*)src;
    *(bf16x8*)&vt[row][seg * 16 + 8] = *(const bf16x8*)(src + 8);
  }
  __syncthreads();
  {
    const int d = tid >> 2, q4 = tid & 3;
    __bf16 tb[16];
    #pragma unroll
    for (int j = 0; j < 16; ++j) tb[j] = vt[q4 * 16 + j][d];
    __bf16* vdst = vst + ((size_t)(h * 64 + ktile)) * 4096 + d * 64;
    const int r7 = d & 7;
    *(bf16x8*)(vdst + ((q4 * 2) ^ r7) * 8)     = *(bf16x8*)tb;
    *(bf16x8*)(vdst + ((q4 * 2 + 1) ^ r7) * 8) = *(bf16x8*)(tb + 8);
  }
}

// ---------------- MFMA flash attention, no-max softmax, split-KV ----------------
// 1552 blocks = 8 XCD x 194: per XCD 2 heads x 97 slots.
//  slot 0..65 : qt = 63 - slot/2 (>=31), part = slot&1 -> kv half; write f32 partials.
//  slot 66..96: qt = 30 - (slot-66), full kv range; write y_bf directly.
// No-max softmax => disjoint-kv partials combine by pure addition (O and l).
__global__ __launch_bounds__(256) void fattn_kernel(const __bf16* __restrict__ qb,
                                                    const __bf16* __restrict__ kst,
                                                    const __bf16* __restrict__ vst,
                                                    __bf16* __restrict__ yb,
                                                    float* __restrict__ opart,
                                                    float* __restrict__ lpart) {
  const int b = blockIdx.x;
  const int xcd = b & 7, s = b >> 3;           // s 0..193
  const int head = xcd * 2 + (s & 1);
  const int slot = s >> 1;                     // 0..96
  int qt, kt0, kt1, part, pid = 0;
  if (slot < 66) {
    qt = 63 - (slot >> 1);
    part = slot & 1;
    const int h1 = (qt + 1) >> 1;
    kt0 = part ? h1 : 0;
    kt1 = part ? qt : h1 - 1;
    pid = (head * 33 + (qt - 31)) * 2 + part;
  } else {
    qt = 30 - (slot - 66);
    part = -1;
    kt0 = 0; kt1 = qt;
  }
  const int tid = threadIdx.x, lane = tid & 63, w = tid >> 6;
  const int c16 = lane & 15, g = lane >> 4;

  __shared__ __align__(16) __bf16 kls[2][4096];
  __shared__ __align__(16) __bf16 vls[2][4096];

  const __bf16* ktiles = kst + (size_t)head * 64 * 4096;
  const __bf16* vtiles = vst + (size_t)head * 64 * 4096;

  #define F_STAGE(kt_, b_)                                                        \
    {                                                                             \
      const char* kb_ = (const char*)(ktiles + (size_t)(kt_) * 4096);             \
      const char* vb_ = (const char*)(vtiles + (size_t)(kt_) * 4096);             \
      _Pragma("unroll")                                                           \
      for (int i_ = 0; i_ < 2; ++i_) {                                            \
        int off_ = i_ * 4096 + w * 1024;                                          \
        gload16(kb_ + off_ + lane * 16, (char*)&kls[b_][0] + off_);               \
        gload16(vb_ + off_ + lane * 16, (char*)&vls[b_][0] + off_);               \
      }                                                                           \
    }

  const int qw0 = qt * 64 + w * 16;

  bf16x8 qf[2];
  #pragma unroll
  for (int kc = 0; kc < 2; ++kc)
    qf[kc] = *(const bf16x8*)(qb + (size_t)(qw0 + c16) * 1024 + head * 64 + kc * 32 + g * 8);

  f32x4 o[4] = {};     // O^T: lane holds O[q=qw0+c16][d=dt*16+g*4+r]
  f32x4 ol = {};       // row-sum via ones-MFMA (all regs identical)
  bf16x4 ones1;
  ones1[0] = ones1[1] = ones1[2] = ones1[3] = (__bf16)1.0f;

  const int m7 = c16 & 7, h2 = g >> 1, lo4 = (g & 1) * 4;
  const __bf16* kp0 = &kls[0][c16 * 64 + ((g ^ m7) * 8)];
  const __bf16* kp1 = &kls[0][c16 * 64 + (((4 + g) ^ m7) * 8)];
  const __bf16* vp0 = &vls[0][c16 * 64 + lo4 + (((0 + h2) ^ m7) * 8)];
  const __bf16* vp1 = &vls[0][c16 * 64 + lo4 + (((2 + h2) ^ m7) * 8)];
  const __bf16* vp2 = &vls[0][c16 * 64 + lo4 + (((4 + h2) ^ m7) * 8)];
  const __bf16* vp3 = &vls[0][c16 * 64 + lo4 + (((6 + h2) ^ m7) * 8)];

  #define F_ONE_ST(B_, st_, vp_)                                                  \
    {                                                                             \
      bf16x4 pv;                                                                  \
      _Pragma("unroll")                                                           \
      for (int r = 0; r < 4; ++r) pv[r] = (__bf16)exp2f(s_[st_][r]);              \
      __builtin_amdgcn_s_setprio(1);                                              \
      ol = mfma16x16x16bf(ones1, pv, ol);                                         \
      _Pragma("unroll")                                                           \
      for (int dt = 0; dt < 4; ++dt) {                                            \
        bf16x4 va = *(const bf16x4*)(vp_ + (B_) * 4096 + dt * 1024);              \
        o[dt] = mfma16x16x16bf(va, pv, o[dt]);                                    \
      }                                                                           \
      __builtin_amdgcn_s_setprio(0);                                              \
    }

  #define F_COMPUTE(B_, kt_)                                                      \
    {                                                                             \
      f32x4 s_[4];                                                                \
      __builtin_amdgcn_s_setprio(1);                                              \
      _Pragma("unroll")                                                           \
      for (int st = 0; st < 4; ++st) {                                            \
        bf16x8 ka0 = *(const bf16x8*)(kp0 + (B_) * 4096 + st * 1024);             \
        bf16x8 ka1 = *(const bf16x8*)(kp1 + (B_) * 4096 + st * 1024);             \
        f32x4 z = {};                                                             \
        z = __builtin_amdgcn_mfma_f32_16x16x32_bf16(ka0, qf[0], z, 0, 0, 0);      \
        s_[st] = __builtin_amdgcn_mfma_f32_16x16x32_bf16(ka1, qf[1], z, 0, 0, 0); \
      }                                                                           \
      __builtin_amdgcn_s_setprio(0);                                              \
      if ((kt_) == qt) {                                                          \
        const int qloc = w * 16 + c16;                                            \
        _Pragma("unroll")                                                         \
        for (int st = 0; st < 4; ++st)                                            \
          _Pragma("unroll")                                                       \
          for (int r = 0; r < 4; ++r)                                             \
            if (st * 16 + g * 4 + r > qloc) s_[st][r] = -1e30f;                   \
      }                                                                           \
      F_ONE_ST(B_, 0, vp0)                                                        \
      F_ONE_ST(B_, 1, vp1)                                                        \
      F_ONE_ST(B_, 2, vp2)                                                        \
      F_ONE_ST(B_, 3, vp3)                                                        \
    }

  F_STAGE(kt0, 0);
  __syncthreads();

  int kt = kt0;
  while (true) {
    if (kt < kt1) F_STAGE(kt + 1, 1);
    F_COMPUTE(0, kt)
    __syncthreads();
    if (kt == kt1) break;
    ++kt;
    if (kt < kt1) F_STAGE(kt + 1, 0);
    F_COMPUTE(1, kt)
    __syncthreads();
    if (kt == kt1) break;
    ++kt;
  }

  if (part >= 0) {
    // --- write f32 partials: O^T rows [q][64d], l per q ---
    float* Op = opart + (size_t)pid * 4096 + (w * 16 + c16) * 64;
    #pragma unroll
    for (int dt = 0; dt < 4; ++dt)
      *(f32x4*)(Op + dt * 16 + g * 4) = o[dt];
    if (g == 0) lpart[pid * 64 + w * 16 + c16] = ol[0];
  } else {
    const float inv = 1.f / ol[0];
    const int q = qw0 + c16;
    #pragma unroll
    for (int dt = 0; dt < 4; ++dt) {
      bf16x4 ov;
      #pragma unroll
      for (int r = 0; r < 4; ++r) ov[r] = (__bf16)(o[dt][r] * inv);
      *(bf16x4*)(yb + (size_t)q * 1024 + head * 64 + dt * 16 + g * 4) = ov;
    }
  }
  #undef F_STAGE
  #undef F_COMPUTE
  #undef F_ONE_ST
}

// ---------------- combine split-KV partials: y = (O0+O1)/(l0+l1) ----------------
// 528 blocks (16 heads x 33 qtiles 31..63), 256 threads; pid pair = (2b, 2b+1).
__global__ __launch_bounds__(256) void combine_kernel(const float* __restrict__ opart,
                                                      const float* __restrict__ lpart,
                                                      __bf16* __restrict__ yb) {
  const int b = blockIdx.x, tid = threadIdx.x;
  const int head = b / 33, qt = 31 + (b - head * 33);
  const int qloc = tid >> 2, d0 = (tid & 3) * 16;
  const float* O0 = opart + (size_t)(2 * b) * 4096 + qloc * 64 + d0;
  const float* O1 = O0 + 4096;
  const float lv = lpart[2 * b * 64 + qloc] + lpart[(2 * b + 1) * 64 + qloc];
  const float inv = 1.f / lv;
  __bf16* dst = yb + (size_t)(qt * 64 + qloc) * 1024 + head * 64 + d0;
  #pragma unroll
  for (int j = 0; j < 4; ++j) {
    f32x4 a = *(const f32x4*)(O0 + j * 4);
    f32x4 c = *(const f32x4*)(O1 + j * 4);
    bf16x4 ov;
    #pragma unroll
    for (int r = 0; r < 4; ++r) ov[r] = (__bf16)((a[r] + c[r]) * inv);
    *(bf16x4*)(dst + j * 4) = ov;
  }
}

extern "C" void kernel_launch(void* const* d_in, const int* in_sizes, int n_in,
                              void* d_out, int out_size, void* d_ws, size_t ws_size,
                              hipStream_t stream) {
  const float* x  = (const float*)d_in[0];
  const float* fc = (const float*)d_in[1];
  const float* fs = (const float*)d_in[2];
  const float* Wa = (const float*)d_in[3];
  const float* Wp = (const float*)d_in[4];
  float* out = (float*)d_out;

  char* ws = (char*)d_ws;
  __bf16* x_bf   = (__bf16*)(ws);              //  8 MB (reused as q_bf after gemm1)
  __bf16* Wa_t   = (__bf16*)(ws + 8388608);    //  6 MB
  __bf16* Wp_t   = (__bf16*)(ws + 14680064);   //  2 MB
  __bf16* y_bf   = (__bf16*)(ws + 16777216);   //  8 MB
  __bf16* qkv_bf = (__bf16*)(ws + 25165824);   // 24 MB (dead after postproc -> partials)
  float*  opart  = (float* )(ws + 25165824);   // 16.5 MB: 1056 x 64x64 f32
  float*  lpart  = (float* )(ws + 42467328);   // 0.27 MB: 1056 x 64 f32
  __bf16* kst    = (__bf16*)(ws + 50331648);   //  8 MB: K tiles  [16][64][64][64] swizzled
  __bf16* vst    = (__bf16*)(ws + 58720256);   //  8 MB: V^T tiles[16][64][64][64] swizzled
  __bf16* q_bf   = x_bf;

  prep_kernel<<<8192, 256, 0, stream>>>(x, Wa, Wp, x_bf, Wa_t, Wp_t);
  gemm_bt_kernel<__bf16><<<768, 256, 0, stream>>>(x_bf, Wa_t, qkv_bf, 4096, 3072, 1024);
  postproc_kernel<<<dim3(64, 16), 256, 0, stream>>>(qkv_bf, fc, fs, q_bf, kst, vst);
  fattn_kernel<<<1552, 256, 0, stream>>>(q_bf, kst, vst, y_bf, opart, lpart);
  combine_kernel<<<528, 256, 0, stream>>>(opart, lpart, y_bf);
  gemm_bt_kernel<float><<<256, 256, 0, stream>>>(y_bf, Wp_t, out, 4096, 1024, 1024);
}

// Round 11
// 229.687 us; speedup vs baseline: 1.0433x; 1.0433x over previous
//
#include <hip/hip_runtime.h>

using f32x4  = __attribute__((ext_vector_type(4))) float;
using bf16x4 = __attribute__((ext_vector_type(4))) __bf16;
using bf16x8 = __attribute__((ext_vector_type(8))) __bf16;
using s16x4  = __attribute__((ext_vector_type(4))) short;

__device__ inline void gload16(const void* g, void* l) {
  __builtin_amdgcn_global_load_lds((const __attribute__((address_space(1))) void*)g,
                                   (__attribute__((address_space(3))) void*)l, 16, 0, 0);
}

__device__ inline f32x4 mfma16x16x16bf(bf16x4 a, bf16x4 b, f32x4 c) {
#if __has_builtin(__builtin_amdgcn_mfma_f32_16x16x16_bf16)
  return __builtin_amdgcn_mfma_f32_16x16x16_bf16(a, b, c, 0, 0, 0);
#else
  return __builtin_amdgcn_mfma_f32_16x16x16bf16_1k(__builtin_bit_cast(s16x4, a),
                                                   __builtin_bit_cast(s16x4, b), c, 0, 0, 0);
#endif
}

#define VM_WAIT4 asm volatile("s_waitcnt vmcnt(4)" ::: "memory")
#define VM_WAIT0 asm volatile("s_waitcnt vmcnt(0)" ::: "memory")
#define BARRIER  __builtin_amdgcn_s_barrier()

// ---------------- prep: pack x->bf16, transpose W_attn & W_proj (one launch) ----------------
__global__ __launch_bounds__(256) void prep_kernel(const float* __restrict__ x,
                                                   const float* __restrict__ Wa,
                                                   const float* __restrict__ Wp,
                                                   __bf16* __restrict__ x_bf,
                                                   __bf16* __restrict__ Wa_t,
                                                   __bf16* __restrict__ Wp_t) {
  const int b = blockIdx.x, tid = threadIdx.x;
  if (b < 4096) {  // pack x
    int i = b * 256 + tid;
    f32x4 v = ((const f32x4*)x)[i];
    bf16x4 o;
    o[0] = (__bf16)v[0]; o[1] = (__bf16)v[1]; o[2] = (__bf16)v[2]; o[3] = (__bf16)v[3];
    ((bf16x4*)x_bf)[i] = o;
    return;
  }
  __shared__ float tile[32][33];
  const int tx = tid & 31, ty = tid >> 5;
  const float* in; __bf16* out; int R, C, c0, r0;
  if (b < 4096 + 3072) {  // Wa^T
    int bx = b - 4096; in = Wa; out = Wa_t; R = 1024; C = 3072;
    c0 = (bx % 96) * 32; r0 = (bx / 96) * 32;
  } else {                // Wp^T
    int bx = b - 7168; in = Wp; out = Wp_t; R = 1024; C = 1024;
    c0 = (bx & 31) * 32; r0 = (bx >> 5) * 32;
  }
  #pragma unroll
  for (int i = 0; i < 32; i += 8)
    tile[ty + i][tx] = in[(size_t)(r0 + ty + i) * C + c0 + tx];
  __syncthreads();
  #pragma unroll
  for (int i = 0; i < 32; i += 8)
    out[(size_t)(c0 + ty + i) * R + r0 + tx] = (__bf16)tile[tx][ty + i];
}

// ---------------- bf16 MFMA GEMM, counted-vmcnt pipeline, XCD-swizzled grid ----------------
template <typename OUT>
__global__ __launch_bounds__(256) void gemm_bt_kernel(const __bf16* __restrict__ A,
                                                      const __bf16* __restrict__ Bt,
                                                      OUT* __restrict__ C,
                                                      int M, int N, int K) {
  const int nwg = gridDim.x, flat = blockIdx.x;
  const int cpx = nwg >> 3;
  const int wg = (flat & 7) * cpx + (flat >> 3);
  const int nbn = N >> 7;
  const int bn = (wg % nbn) * 128, bm = (wg / nbn) * 128;

  const int tid = threadIdx.x;
  const int lane = tid & 63, wid = tid >> 6;
  const int wm = (wid >> 1) * 64, wn = (wid & 1) * 64;
  const int l15 = lane & 15, lhi = lane >> 4;
  __shared__ __align__(16) __bf16 As[2][4096];  // [128][32]
  __shared__ __align__(16) __bf16 Bs[2][4096];
  f32x4 acc[4][4] = {};

  const int rrow = wid * 16 + (lane >> 2);
  const int schunk = lane & 3;

  // 4 loads per thread per stage
  #define G_STAGE(k0_, b_)                                                              \
    {                                                                                   \
      _Pragma("unroll")                                                                 \
      for (int i_ = 0; i_ < 2; ++i_) {                                                  \
        int row_ = i_ * 64 + rrow;                                                      \
        int lch_ = schunk ^ (row_ & 3);                                                 \
        gload16(A + (size_t)(bm + row_) * K + (k0_) + lch_ * 8,                         \
                (char*)&As[b_][0] + i_ * 4096 + wid * 1024);                            \
        gload16(Bt + (size_t)(bn + row_) * K + (k0_) + lch_ * 8,                        \
                (char*)&Bs[b_][0] + i_ * 4096 + wid * 1024);                            \
      }                                                                                 \
    }

  G_STAGE(0, 0);
  const int nk = K >> 5;
  for (int t = 0; t < nk; ++t) {
    const int cur = t & 1;
    if (t + 1 < nk) { G_STAGE((t + 1) * 32, cur ^ 1); VM_WAIT4; } else { VM_WAIT0; }
    BARRIER;  // buf cur resident for all waves
    bf16x8 af[4], bfr[4];
    #pragma unroll
    for (int i = 0; i < 4; ++i) {
      int row = wm + i * 16 + l15;
      af[i] = *(const bf16x8*)&As[cur][row * 32 + ((lhi ^ (row & 3)) * 8)];
    }
    #pragma unroll
    for (int j = 0; j < 4; ++j) {
      int row = wn + j * 16 + l15;
      bfr[j] = *(const bf16x8*)&Bs[cur][row * 32 + ((lhi ^ (row & 3)) * 8)];
    }
    #pragma unroll
    for (int i = 0; i < 4; ++i)
      #pragma unroll
      for (int j = 0; j < 4; ++j)
        acc[i][j] = __builtin_amdgcn_mfma_f32_16x16x32_bf16(af[i], bfr[j], acc[i][j], 0, 0, 0);
    BARRIER;  // all reads of buf cur done; next iter may overwrite it
  }
  #pragma unroll
  for (int i = 0; i < 4; ++i)
    #pragma unroll
    for (int j = 0; j < 4; ++j)
      #pragma unroll
      for (int r = 0; r < 4; ++r)
        C[(size_t)(bm + wm + i * 16 + lhi * 4 + r) * N + (bn + wn + j * 16 + l15)] =
            (OUT)acc[i][j][r];
  #undef G_STAGE
}

// ---------------- postproc: RoPE+pack q; K,V^T -> swizzled 64x64 tiles ----------------
__global__ __launch_bounds__(256) void postproc_kernel(const __bf16* __restrict__ qkv,
                                                       const float* __restrict__ fc,
                                                       const float* __restrict__ fs,
                                                       __bf16* __restrict__ qb,
                                                       __bf16* __restrict__ kst,
                                                       __bf16* __restrict__ vst) {
  const int ktile = blockIdx.x, h = blockIdx.y;
  const int tid = threadIdx.x;
  const int row = tid >> 2, seg = tid & 3;
  const int t = ktile * 64 + row;
  __shared__ __bf16 vt[64][72];

  float cs[8], sn[8];
  #pragma unroll
  for (int p = 0; p < 8; ++p) {
    cs[p] = fc[t * 32 + seg * 8 + p];
    sn[p] = fs[t * 32 + seg * 8 + p];
  }
  const float QS = 0.125f * 1.4426950408889634f;  // 1/sqrt(64) * log2(e)

  {
    const __bf16* src = qkv + (size_t)t * 3072 + h * 64 + seg * 16;
    bf16x8 a = *(const bf16x8*)src, b = *(const bf16x8*)(src + 8);
    float v[16];
    #pragma unroll
    for (int i = 0; i < 8; ++i) { v[i] = (float)a[i]; v[8 + i] = (float)b[i]; }
    __bf16 ob[16];
    #pragma unroll
    for (int p = 0; p < 8; ++p) {
      ob[2 * p]     = (__bf16)((v[2 * p] * cs[p] - v[2 * p + 1] * sn[p]) * QS);
      ob[2 * p + 1] = (__bf16)((v[2 * p] * sn[p] + v[2 * p + 1] * cs[p]) * QS);
    }
    __bf16* dst = qb + (size_t)t * 1024 + h * 64 + seg * 16;
    *(bf16x8*)dst = *(bf16x8*)ob;
    *(bf16x8*)(dst + 8) = *(bf16x8*)(ob + 8);
  }
  {
    const __bf16* src = qkv + (size_t)t * 3072 + 1024 + h * 64 + seg * 16;
    bf16x8 a = *(const bf16x8*)src, b = *(const bf16x8*)(src + 8);
    float v[16];
    #pragma unroll
    for (int i = 0; i < 8; ++i) { v[i] = (float)a[i]; v[8 + i] = (float)b[i]; }
    __bf16 ob[16];
    #pragma unroll
    for (int p = 0; p < 8; ++p) {
      ob[2 * p]     = (__bf16)(v[2 * p] * cs[p] - v[2 * p + 1] * sn[p]);
      ob[2 * p + 1] = (__bf16)(v[2 * p] * sn[p] + v[2 * p + 1] * cs[p]);
    }
    __bf16* kdst = kst + ((size_t)(h * 64 + ktile)) * 4096 + row * 64;
    const int r7 = row & 7;
    *(bf16x8*)(kdst + ((seg * 2) ^ r7) * 8)     = *(bf16x8*)ob;
    *(bf16x8*)(kdst + ((seg * 2 + 1) ^ r7) * 8) = *(bf16x8*)(ob + 8);
  }
  {
    const __bf16* src = qkv + (size_t)t * 3072 + 2048 + h * 64 + seg * 16;
    *(bf16x8*)&vt[row][seg * 16]     = *(const bf16x8*)src;
    *(bf16x8*)&vt[row][seg * 16 + 8] = *(const bf16x8*)(src + 8);
  }
  __syncthreads();
  {
    const int d = tid >> 2, q4 = tid & 3;
    __bf16 tb[16];
    #pragma unroll
    for (int j = 0; j < 16; ++j) tb[j] = vt[q4 * 16 + j][d];
    __bf16* vdst = vst + ((size_t)(h * 64 + ktile)) * 4096 + d * 64;
    const int r7 = d & 7;
    *(bf16x8*)(vdst + ((q4 * 2) ^ r7) * 8)     = *(bf16x8*)tb;
    *(bf16x8*)(vdst + ((q4 * 2 + 1) ^ r7) * 8) = *(bf16x8*)(tb + 8);
  }
}

// ---------------- MFMA flash attention, no-max softmax, counted-vmcnt pipeline ----------------
// 1024 blocks = 8 XCD x (2 heads x 64 qtiles desc), 256 threads = 4 waves x 16 q-rows.
// Per kv-tile: {STAGE(next); vmcnt(4); barrier; COMPUTE(cur); barrier} -- loads stay in
// flight across barriers (T4); no vmcnt(0) drain in the main loop.
__global__ __launch_bounds__(256) void fattn_kernel(const __bf16* __restrict__ qb,
                                                    const __bf16* __restrict__ kst,
                                                    const __bf16* __restrict__ vst,
                                                    __bf16* __restrict__ yb) {
  const int b = blockIdx.x;
  const int xcd = b & 7, slot = b >> 3;        // slot 0..127
  const int head = xcd * 2 + (slot & 1);
  const int qt = 63 - (slot >> 1);             // descending: long blocks first
  const int tid = threadIdx.x, lane = tid & 63, w = tid >> 6;
  const int c16 = lane & 15, g = lane >> 4;

  __shared__ __align__(16) __bf16 kls[2][4096];
  __shared__ __align__(16) __bf16 vls[2][4096];

  const __bf16* ktiles = kst + (size_t)head * 64 * 4096;
  const __bf16* vtiles = vst + (size_t)head * 64 * 4096;

  // 4 loads per thread per stage
  #define F_STAGE(kt_, b_)                                                        \
    {                                                                             \
      const char* kb_ = (const char*)(ktiles + (size_t)(kt_) * 4096);             \
      const char* vb_ = (const char*)(vtiles + (size_t)(kt_) * 4096);             \
      _Pragma("unroll")                                                           \
      for (int i_ = 0; i_ < 2; ++i_) {                                            \
        int off_ = i_ * 4096 + w * 1024;                                          \
        gload16(kb_ + off_ + lane * 16, (char*)&kls[b_][0] + off_);               \
        gload16(vb_ + off_ + lane * 16, (char*)&vls[b_][0] + off_);               \
      }                                                                           \
    }

  const int qw0 = qt * 64 + w * 16;

  bf16x8 qf[2];
  #pragma unroll
  for (int kc = 0; kc < 2; ++kc)
    qf[kc] = *(const bf16x8*)(qb + (size_t)(qw0 + c16) * 1024 + head * 64 + kc * 32 + g * 8);

  f32x4 o[4] = {};     // O^T: lane holds O[q=qw0+c16][d=dt*16+g*4+r]
  f32x4 ol = {};       // row-sum via ones-MFMA (all regs identical)
  bf16x4 ones1;
  ones1[0] = ones1[1] = ones1[2] = ones1[3] = (__bf16)1.0f;

  const int m7 = c16 & 7, h2 = g >> 1, lo4 = (g & 1) * 4;
  const __bf16* kp0 = &kls[0][c16 * 64 + ((g ^ m7) * 8)];
  const __bf16* kp1 = &kls[0][c16 * 64 + (((4 + g) ^ m7) * 8)];
  const __bf16* vp0 = &vls[0][c16 * 64 + lo4 + (((0 + h2) ^ m7) * 8)];
  const __bf16* vp1 = &vls[0][c16 * 64 + lo4 + (((2 + h2) ^ m7) * 8)];
  const __bf16* vp2 = &vls[0][c16 * 64 + lo4 + (((4 + h2) ^ m7) * 8)];
  const __bf16* vp3 = &vls[0][c16 * 64 + lo4 + (((6 + h2) ^ m7) * 8)];

  #define F_ONE_ST(B_, st_, vp_)                                                  \
    {                                                                             \
      bf16x4 pv;                                                                  \
      _Pragma("unroll")                                                           \
      for (int r = 0; r < 4; ++r) pv[r] = (__bf16)exp2f(s_[st_][r]);              \
      __builtin_amdgcn_s_setprio(1);                                              \
      ol = mfma16x16x16bf(ones1, pv, ol);                                         \
      _Pragma("unroll")                                                           \
      for (int dt = 0; dt < 4; ++dt) {                                            \
        bf16x4 va = *(const bf16x4*)(vp_ + (B_) * 4096 + dt * 1024);              \
        o[dt] = mfma16x16x16bf(va, pv, o[dt]);                                    \
      }                                                                           \
      __builtin_amdgcn_s_setprio(0);                                              \
    }

  #define F_COMPUTE(B_, kt_)                                                      \
    {                                                                             \
      f32x4 s_[4];                                                                \
      __builtin_amdgcn_s_setprio(1);                                              \
      _Pragma("unroll")                                                           \
      for (int st = 0; st < 4; ++st) {                                            \
        bf16x8 ka0 = *(const bf16x8*)(kp0 + (B_) * 4096 + st * 1024);             \
        bf16x8 ka1 = *(const bf16x8*)(kp1 + (B_) * 4096 + st * 1024);             \
        f32x4 z = {};                                                             \
        z = __builtin_amdgcn_mfma_f32_16x16x32_bf16(ka0, qf[0], z, 0, 0, 0);      \
        s_[st] = __builtin_amdgcn_mfma_f32_16x16x32_bf16(ka1, qf[1], z, 0, 0, 0); \
      }                                                                           \
      __builtin_amdgcn_s_setprio(0);                                              \
      if ((kt_) == qt) {                                                          \
        const int qloc = w * 16 + c16;                                            \
        _Pragma("unroll")                                                         \
        for (int st = 0; st < 4; ++st)                                            \
          _Pragma("unroll")                                                       \
          for (int r = 0; r < 4; ++r)                                             \
            if (st * 16 + g * 4 + r > qloc) s_[st][r] = -1e30f;                   \
      }                                                                           \
      F_ONE_ST(B_, 0, vp0)                                                        \
      F_ONE_ST(B_, 1, vp1)                                                        \
      F_ONE_ST(B_, 2, vp2)                                                        \
      F_ONE_ST(B_, 3, vp3)                                                        \
    }

  F_STAGE(0, 0);

  int kt = 0;
  while (true) {
    if (kt < qt) { F_STAGE(kt + 1, 1); VM_WAIT4; } else { VM_WAIT0; }
    BARRIER;               // buf0 resident for all waves
    F_COMPUTE(0, kt)
    BARRIER;               // all reads of buf0 done
    if (kt == qt) break;
    ++kt;
    if (kt < qt) { F_STAGE(kt + 1, 0); VM_WAIT4; } else { VM_WAIT0; }
    BARRIER;               // buf1 resident
    F_COMPUTE(1, kt)
    BARRIER;               // all reads of buf1 done
    if (kt == qt) break;
    ++kt;
  }

  const float inv = 1.f / ol[0];
  const int q = qw0 + c16;
  #pragma unroll
  for (int dt = 0; dt < 4; ++dt) {
    bf16x4 ov;
    #pragma unroll
    for (int r = 0; r < 4; ++r) ov[r] = (__bf16)(o[dt][r] * inv);
    *(bf16x4*)(yb + (size_t)q * 1024 + head * 64 + dt * 16 + g * 4) = ov;
  }
  #undef F_STAGE
  #undef F_COMPUTE
  #undef F_ONE_ST
}

extern "C" void kernel_launch(void* const* d_in, const int* in_sizes, int n_in,
                              void* d_out, int out_size, void* d_ws, size_t ws_size,
                              hipStream_t stream) {
  const float* x  = (const float*)d_in[0];
  const float* fc = (const float*)d_in[1];
  const float* fs = (const float*)d_in[2];
  const float* Wa = (const float*)d_in[3];
  const float* Wp = (const float*)d_in[4];
  float* out = (float*)d_out;

  char* ws = (char*)d_ws;
  __bf16* x_bf   = (__bf16*)(ws);              //  8 MB (reused as q_bf after gemm1)
  __bf16* Wa_t   = (__bf16*)(ws + 8388608);    //  6 MB
  __bf16* Wp_t   = (__bf16*)(ws + 14680064);   //  2 MB
  __bf16* y_bf   = (__bf16*)(ws + 16777216);   //  8 MB
  __bf16* qkv_bf = (__bf16*)(ws + 25165824);   // 24 MB: [4096][3072] bf16
  __bf16* kst    = (__bf16*)(ws + 50331648);   //  8 MB: K tiles  [16][64][64][64] swizzled
  __bf16* vst    = (__bf16*)(ws + 58720256);   //  8 MB: V^T tiles[16][64][64][64] swizzled
  __bf16* q_bf   = x_bf;

  prep_kernel<<<8192, 256, 0, stream>>>(x, Wa, Wp, x_bf, Wa_t, Wp_t);
  gemm_bt_kernel<__bf16><<<768, 256, 0, stream>>>(x_bf, Wa_t, qkv_bf, 4096, 3072, 1024);
  postproc_kernel<<<dim3(64, 16), 256, 0, stream>>>(qkv_bf, fc, fs, q_bf, kst, vst);
  fattn_kernel<<<1024, 256, 0, stream>>>(q_bf, kst, vst, y_bf);
  gemm_bt_kernel<float><<<256, 256, 0, stream>>>(y_bf, Wp_t, out, 4096, 1024, 1024);
}